// Round 2
// baseline (150.100 us; speedup 1.0000x reference)
//
#include <hip/hip_runtime.h>
#include <hip/hip_fp16.h>
#include <math.h>

#define Bv 4096
#define Sv 64
#define Ev 128
#define Hv 256
#define Cv 18
#define Mrows 16
#define WRDS 3072    // words per step buffer: kb0..11 (emb kb0-3, h kb4-11)

typedef _Float16 hfrag __attribute__((ext_vector_type(8)));
using f4v = __attribute__((ext_vector_type(4))) float;

#define LO_SCALE 2048.0f            // 2^11 on w1_lo (FC1 only)
#define LO_DESCALE (1.0f / 2048.0f)

// XOR swizzle: flips bits 2-4 by a hash of higher bits. Bits 0-1 preserved
// -> b128/uint2/b32 contiguity kept; balances scattered writes across banks
// while reads remain the canonical conflict-free lane*16B pattern.
__device__ inline int SW(int o) {
    return o ^ ((((o >> 5) ^ (o >> 8)) & 7) << 2);
}

__device__ inline float fast_tanh(float x) {
    // tanh(x) = 1 - 2/(exp2(2x*log2e)+1); single fmul feeding v_exp_f32
    float e = __builtin_amdgcn_exp2f(x * 2.8853900817779268f);
    return 1.0f - 2.0f * __builtin_amdgcn_rcpf(e + 1.0f);
}

__device__ inline unsigned pk_h2(float a, float b) {
    unsigned ua = __half_as_ushort(__float2half_rn(a));
    unsigned ub = __half_as_ushort(__float2half_rn(b));
    return ua | (ub << 16);
}

// ---- kernel A: build MFMA fragments: rnn W (f16 hi only), W1 (hi + lo*2^11) ----
__global__ void build_frags(const float* __restrict__ W_ih,
                            const float* __restrict__ W_hh,
                            const float* __restrict__ W1,
                            unsigned* __restrict__ wfh,
                            unsigned* __restrict__ wf1h, unsigned* __restrict__ wf1l) {
    int f = blockIdx.x * 256 + threadIdx.x;   // 0..20479
    bool isrnn = f < 12288;
    int g = isrnn ? f : f - 12288;
    int lane = g & 63, tile = (g >> 6) & 15, kb = g >> 10;
    int q = lane >> 4, col = lane & 15;
    int n = tile * 16 + col;
    unsigned hu[8], lu[8];
    #pragma unroll
    for (int j = 0; j < 8; ++j) {
        int k = kb * 32 + q * 8 + j;
        float x;
        if (isrnn) x = (k < Ev) ? W_ih[n * Ev + k] : W_hh[n * Hv + (k - Ev)];
        else       x = W1[n * Hv + k];
        __half h = __float2half_rn(x);
        hu[j] = __half_as_ushort(h);
        float l = (x - __half2float(h)) * LO_SCALE;
        lu[j] = __half_as_ushort(__float2half_rn(l));
    }
    unsigned* oh = (isrnn ? wfh : wf1h) + (size_t)g * 4;
    #pragma unroll
    for (int d = 0; d < 4; ++d) oh[d] = hu[2 * d] | (hu[2 * d + 1] << 16);
    if (!isrnn) {
        unsigned* ol = wf1l + (size_t)g * 4;
        #pragma unroll
        for (int d = 0; d < 4; ++d) ol[d] = lu[2 * d] | (lu[2 * d + 1] << 16);
    }
}

// ---- kernel B: fused recurrence + FC head ----
// 16 waves x 1 N-tile each (was 8x2): 4 waves/SIMD so the CU scheduler can
// co-issue one wave's MFMA burst under another wave's tanh/pack epilogue
// (MFMA and VALU are separate pipes; phase-locked 2-wave config left the
// MFMA pipe idle ~70% of each step). Per-wave: 12 MFMA + 8 tanh per step.
__global__ __launch_bounds__(1024, 4) void rnn_fused(
    const int* __restrict__ x_in, const int* __restrict__ x_len,
    const float* __restrict__ emb,
    const unsigned* __restrict__ wfh,
    const unsigned* __restrict__ wf1h, const unsigned* __restrict__ wf1l,
    const float* __restrict__ b_ih, const float* __restrict__ b_hh,
    const float* __restrict__ b1, const float* __restrict__ W2,
    const float* __restrict__ b2, float* __restrict__ out)
{
    __shared__ unsigned SH[2 * WRDS];   // 24 KB step buffers (f16 A fragments)
    __shared__ unsigned LF[2048];       // 8 KB last-h fragments
    float* yb = reinterpret_cast<float*>(SH);   // fc y buffer aliases SH after loop

    const int tid = threadIdx.x;
    const int lane = tid & 63, w = tid >> 6;     // wave 0..15, one N-tile each
    const int q = lane >> 4, col = lane & 15;
    const int rb = blockIdx.x * Mrows;

    // resident W: tile w, f16 hi, all 12 kb (48 regs)
    hfrag wh[12];
    #pragma unroll
    for (int kb = 0; kb < 12; ++kb) {
        int fid = (kb * 16 + w) * 64 + lane;
        wh[kb] = *reinterpret_cast<const hfrag*>(&wfh[(size_t)fid * 4]);
    }
    #pragma unroll
    for (int kb = 0; kb < 12; ++kb) asm volatile("" : "+v"(wh[kb]));

    // bias folded into MFMA C-init (chain 0)
    f4v bcv;
    #pragma unroll
    for (int r = 0; r < 4; ++r) {
        int n = w * 16 + 4 * q + r;
        bcv[r] = b_ih[n] + b_hh[n];
    }
    const int len_c = x_len[rb + col];
    int tmax = len_c;
    #pragma unroll
    for (int m = 1; m < 16; m <<= 1) {
        int o = __shfl_xor(tmax, m, 64);
        tmax = tmax > o ? tmax : o;
    }

    // zero h region of buffer 0 (words 1024..3071; SW permutes within)
    for (int u = tid; u < 2048; u += 1024) SH[1024 + u] = 0u;

    // emb staging geometry: thread stages 2 consecutive k of one row (1 word)
    const int em = tid >> 6;            // row 0..15 (== wave)
    const int ek = (tid & 63) * 2;      // k 0..126 step 2
    const int eo = (ek >> 5) * 256 + ((((ek >> 3) & 3) * 16 + em) * 4) + ((ek >> 1) & 3);
    const int* xrow = x_in + (rb + em) * Sv;

    // stage emb for t=0; prefetch row for t=1 (depth-2 pipeline)
    {
        float2 e0 = *(const float2*)&emb[(size_t)xrow[0] * Ev + ek];
        SH[SW(eo)] = pk_h2(e0.x, e0.y);
    }
    float2 ev_cur = *(const float2*)&emb[(size_t)xrow[1] * Ev + ek];
    uint2 snap = make_uint2(0u, 0u);
    __syncthreads();

    #pragma unroll 1
    for (int t = 0; t < tmax; ++t) {
        const int rbuf = (t & 1) * WRDS;
        const int wbuf = ((t + 1) & 1) * WRDS;

        // prefetch emb row for t+2 (token read is L1-hot global, vmem pipe idle)
        float2 ev_next = ev_cur;
        if (t + 2 < Sv) {
            int tok = xrow[t + 2];
            ev_next = *(const float2*)&emb[(size_t)tok * Ev + ek];
        }

        // 4 accumulator chains (depth 3), bias folded into chain 0
        f4v z = {0.f, 0.f, 0.f, 0.f};
        f4v a0 = bcv, a1 = z, a2 = z, a3 = z;

        #pragma unroll
        for (int kb = 0; kb < 12; ++kb) {
            hfrag ah = *reinterpret_cast<const hfrag*>(&SH[rbuf + SW(kb * 256 + lane * 4)]);
            switch (kb & 3) {
                case 0: a0 = __builtin_amdgcn_mfma_f32_16x16x32_f16(wh[kb], ah, a0, 0, 0, 0); break;
                case 1: a1 = __builtin_amdgcn_mfma_f32_16x16x32_f16(wh[kb], ah, a1, 0, 0, 0); break;
                case 2: a2 = __builtin_amdgcn_mfma_f32_16x16x32_f16(wh[kb], ah, a2, 0, 0, 0); break;
                default: a3 = __builtin_amdgcn_mfma_f32_16x16x32_f16(wh[kb], ah, a3, 0, 0, 0); break;
            }
        }

        // stage emb for t+1 early: independent of this step's MFMA results,
        // so it overlaps the MFMA tail instead of extending the epilogue.
        if (t + 1 < Sv) {
            SH[wbuf + SW(eo)] = pk_h2(ev_cur.x, ev_cur.y);
        }

        // epilogue: lane holds h[m=col][n = w*16 + 4q + r]
        {
            f4v s = (a0 + a1) + (a2 + a3);
            float hv[4];
            #pragma unroll
            for (int r = 0; r < 4; ++r)
                hv[r] = fast_tanh(s[r]);
            const int dl = ((w & 1) * 2 + (q >> 1)) * 16 + col;
            const uint2 hu = make_uint2(pk_h2(hv[0], hv[1]), pk_h2(hv[2], hv[3]));
            const int oAH = (4 + (w >> 1)) * 256 + dl * 4 + (q & 1) * 2;
            *reinterpret_cast<uint2*>(&SH[wbuf + SW(oAH)]) = hu;
            if (t == len_c - 1) snap = hu;   // register snapshot, no LDS write
        }
        ev_cur = ev_next;
        __syncthreads();
    }

    // ---- write last-h snapshot to LF once ----
    {
        const int dl = ((w & 1) * 2 + (q >> 1)) * 16 + col;
        const int oLH = (w >> 1) * 256 + dl * 4 + (q & 1) * 2;
        *reinterpret_cast<uint2*>(&LF[SW(oLH)]) = snap;
    }
    __syncthreads();

    // ---- fused FC1 (MFMA, f16 hi+lo) on LF; wave w -> output tile w ----
    f4v fH, fL;
    {
        float4 bb = *(const float4*)&b1[w * 16 + 4 * q];
        fH = (f4v){bb.x, bb.y, bb.z, bb.w};
        fL = (f4v){0.f, 0.f, 0.f, 0.f};
    }
    #pragma unroll
    for (int kb = 0; kb < 8; ++kb) {
        hfrag ah = *reinterpret_cast<const hfrag*>(&LF[SW(kb * 256 + lane * 4)]);
        int fid = (kb * 16 + w) * 64 + lane;
        hfrag w0h = *reinterpret_cast<const hfrag*>(&wf1h[(size_t)fid * 4]);
        hfrag w0l = *reinterpret_cast<const hfrag*>(&wf1l[(size_t)fid * 4]);
        fH = __builtin_amdgcn_mfma_f32_16x16x32_f16(w0h, ah, fH, 0, 0, 0);
        fL = __builtin_amdgcn_mfma_f32_16x16x32_f16(w0l, ah, fL, 0, 0, 0);
    }

    // y = relu(...) into yb (aliases SH; step buffers dead, LF untouched)
    {
        int n0 = w * 16 + 4 * q;
        float4 yv;
        yv.x = fmaxf(fH[0] + fL[0] * LO_DESCALE, 0.f);
        yv.y = fmaxf(fH[1] + fL[1] * LO_DESCALE, 0.f);
        yv.z = fmaxf(fH[2] + fL[2] * LO_DESCALE, 0.f);
        yv.w = fmaxf(fH[3] + fL[3] * LO_DESCALE, 0.f);
        *reinterpret_cast<float4*>(&yb[col * 260 + n0]) = yv;
    }
    __syncthreads();

    // ---- FC2: 16 x 18 dots of length 256 ----
    if (tid < Mrows * Cv) {
        int r = tid & 15, cc = tid >> 4;
        float s = b2[cc];
        #pragma unroll 8
        for (int k4 = 0; k4 < Hv / 4; ++k4) {
            float4 yv = *reinterpret_cast<const float4*>(&yb[r * 260 + 4 * k4]);
            float4 wv2 = *(const float4*)&W2[cc * Hv + 4 * k4];
            s = fmaf(yv.x, wv2.x, s);
            s = fmaf(yv.y, wv2.y, s);
            s = fmaf(yv.z, wv2.z, s);
            s = fmaf(yv.w, wv2.w, s);
        }
        out[(rb + r) * Cv + cc] = s;
    }
}

extern "C" void kernel_launch(void* const* d_in, const int* in_sizes, int n_in,
                              void* d_out, int out_size, void* d_ws, size_t ws_size,
                              hipStream_t stream) {
    const int*   x_in  = (const int*)  d_in[0];
    const int*   x_len = (const int*)  d_in[1];
    const float* emb   = (const float*)d_in[2];
    const float* W_ih  = (const float*)d_in[3];
    const float* W_hh  = (const float*)d_in[4];
    const float* b_ih  = (const float*)d_in[5];
    const float* b_hh  = (const float*)d_in[6];
    const float* W1    = (const float*)d_in[7];
    const float* b1    = (const float*)d_in[8];
    const float* W2    = (const float*)d_in[9];
    const float* b2    = (const float*)d_in[10];
    float* out = (float*)d_out;

    unsigned* wfh  = (unsigned*)d_ws;         // 12288 frags * 16 B
    unsigned* wf1h = wfh  + 12288 * 4;        // 8192 * 16 B
    unsigned* wf1l = wf1h + 8192 * 4;         // 8192 * 16 B

    build_frags<<<80, 256, 0, stream>>>(W_ih, W_hh, W1, wfh, wf1h, wf1l);
    rnn_fused<<<Bv / Mrows, 1024, 0, stream>>>(x_in, x_len, emb, wfh,
                                               wf1h, wf1l, b_ih, b_hh,
                                               b1, W2, b2, out);
}